// Round 1
// baseline (409.345 us; speedup 1.0000x reference)
//
#include <hip/hip_runtime.h>
#include <hip/hip_bf16.h>
#include <float.h>
#include <math.h>

// Problem constants (B=8, T=4096, D=128, K=2048)
#define NTOK 32768
#define DD 128
#define HH 64
#define KK 2048
#define NWAVE 4
#define CPW (KK / NWAVE)   // 512 codes per wave

// d_out flat layout (all float32):
#define OFF_OUT 0
#define OFF_IDS (NTOK * HH)            // 2097152
#define OFF_COM (OFF_IDS + NTOK)       // 2130176
#define OFF_COD (OFF_COM + NTOK)       // 2162944

// ---------------------------------------------------------------------------
// Kernel A: per-code stats. stats[k] = {0.5*sum(u), sum(mu^2), 1/(2*sum(exp u))}
// ---------------------------------------------------------------------------
__global__ __launch_bounds__(256) void stats_kernel(const float* __restrict__ emb,
                                                    float4* __restrict__ stats) {
    int k = blockIdx.x * blockDim.x + threadIdx.x;
    if (k >= KK) return;
    const float4* row = (const float4*)(emb + (size_t)k * DD);
    float b2 = 0.f, su = 0.f, se = 0.f;
#pragma unroll
    for (int j = 0; j < 16; ++j) {
        float4 m = row[j];
        b2 += m.x * m.x + m.y * m.y + m.z * m.z + m.w * m.w;
    }
#pragma unroll
    for (int j = 16; j < 32; ++j) {
        float4 u = row[j];
        su += u.x + u.y + u.z + u.w;
        se += __expf(u.x) + __expf(u.y) + __expf(u.z) + __expf(u.w);
    }
    stats[k] = make_float4(0.5f * su, b2, 1.0f / (2.0f * se), 0.f);
}

// ---------------------------------------------------------------------------
// fp64 exact distance (token-constant -sum(log sigma_i) dropped consistently)
// ---------------------------------------------------------------------------
__device__ double dist_fp64(const float* xr, const float* er) {
    double dot = 0.0, b2 = 0.0, le = 0.0, den = 0.0, c = 0.0;
    for (int h = 0; h < HH; ++h) {
        double mi = (double)xr[h];
        double me = (double)er[h];
        dot += mi * me;
        b2 += me * me;
        c += mi * mi;
        double ue = (double)er[HH + h];
        double ui = (double)xr[HH + h];
        le += ue;
        den += exp(ue);
        c += exp(ui);
    }
    return 0.5 * le + (c + b2 - 2.0 * dot) / (2.0 * den);
}

// ---------------------------------------------------------------------------
// Kernel B: main. 1 block = 64 tokens; lane = token; 4 waves split the codes.
// ---------------------------------------------------------------------------
__global__ __launch_bounds__(256) void vq_kernel(const float* __restrict__ x,
                                                 const float* __restrict__ emb,
                                                 const float* __restrict__ z,
                                                 const float4* __restrict__ stats,
                                                 float* __restrict__ out) {
    __shared__ float s_d1[NWAVE][64];
    __shared__ float s_d2[NWAVE][64];
    __shared__ int   s_i1[NWAVE][64];
    __shared__ int   s_i2[NWAVE][64];
    __shared__ int   s_bid[64];
    __shared__ float s_ssd[64][4];

    const int tid  = threadIdx.x;
    const int lane = tid & 63;
    const int wid  = __builtin_amdgcn_readfirstlane(tid >> 6);  // wave-uniform SGPR
    const int tok  = blockIdx.x * 64 + lane;

    // ---- load mu_i into registers, compute C = sum(mu^2) + sum(exp(x_h)) ----
    float mu[HH];
    float C = 0.f;
    const float4* xr = (const float4*)(x + (size_t)tok * DD);
#pragma unroll
    for (int j = 0; j < 16; ++j) {
        float4 m = xr[j];
        mu[4 * j + 0] = m.x;
        mu[4 * j + 1] = m.y;
        mu[4 * j + 2] = m.z;
        mu[4 * j + 3] = m.w;
        C += m.x * m.x + m.y * m.y + m.z * m.z + m.w * m.w;
    }
#pragma unroll
    for (int j = 16; j < 32; ++j) {
        float4 u = xr[j];
        C += __expf(u.x) + __expf(u.y) + __expf(u.z) + __expf(u.w);
    }

    // ---- scan this wave's code range, track top-2 ----
    float d1 = FLT_MAX, d2 = FLT_MAX;
    int   i1 = 0, i2 = 0;
    const int kbase = wid * CPW;
    for (int kk = 0; kk < CPW; ++kk) {
        const int k = kbase + kk;                      // wave-uniform
        const float4* cp = (const float4*)(emb + (size_t)k * DD);
        const float4  st = stats[k];
        float a0 = 0.f, a1 = 0.f, a2 = 0.f, a3 = 0.f;
#pragma unroll
        for (int j = 0; j < 16; ++j) {
            float4 e = cp[j];
            a0 = fmaf(mu[4 * j + 0], e.x, a0);
            a1 = fmaf(mu[4 * j + 1], e.y, a1);
            a2 = fmaf(mu[4 * j + 2], e.z, a2);
            a3 = fmaf(mu[4 * j + 3], e.w, a3);
        }
        const float dot = (a0 + a1) + (a2 + a3);
        const float d = st.x + (C + st.y - 2.0f * dot) * st.z;
        if (d < d1) {
            d2 = d1; i2 = i1; d1 = d; i1 = k;
        } else if (d < d2) {
            d2 = d; i2 = k;
        }
    }
    s_d1[wid][lane] = d1; s_i1[wid][lane] = i1;
    s_d2[wid][lane] = d2; s_i2[wid][lane] = i2;
    __syncthreads();

    // ---- combine across waves + near-tie fp64 rerank (threads 0..63) ----
    if (tid < 64) {
        float b1 = FLT_MAX, b2v = FLT_MAX;
        int   j1 = 0, j2 = 0;
        for (int w = 0; w < NWAVE; ++w) {
            float dA = s_d1[w][tid]; int iA = s_i1[w][tid];
            float dB = s_d2[w][tid]; int iB = s_i2[w][tid];
            if (dA < b1)      { b2v = b1; j2 = j1; b1 = dA; j1 = iA; }
            else if (dA < b2v){ b2v = dA; j2 = iA; }
            if (dB < b1)      { b2v = b1; j2 = j1; b1 = dB; j1 = iB; }
            else if (dB < b2v){ b2v = dB; j2 = iB; }
        }
        const int gtok = blockIdx.x * 64 + tid;
        if (b2v - b1 < 2e-4f * (1.0f + fabsf(b1))) {
            double e1 = dist_fp64(x + (size_t)gtok * DD, emb + (size_t)j1 * DD);
            double e2 = dist_fp64(x + (size_t)gtok * DD, emb + (size_t)j2 * DD);
            if (e2 < e1 || (e2 == e1 && j2 < j1)) j1 = j2;
        }
        s_bid[tid] = j1;
        out[OFF_IDS + gtok] = (float)j1;  // ids stored as float values
    }
    __syncthreads();

    // ---- epilogue: 4 threads per token, 16 dims each ----
    {
        const int ltok = tid >> 2;
        const int q    = tid & 3;
        const int gt   = blockIdx.x * 64 + ltok;
        const int code = s_bid[ltok];
        const float* er  = emb + (size_t)code * DD;
        const float* xr2 = x + (size_t)gt * DD;
        const float* zr  = z + (size_t)gt * HH;
        float ssd = 0.f;
#pragma unroll
        for (int j = 0; j < 4; ++j) {
            const int h0 = q * 16 + j * 4;
            float4 qm = *(const float4*)(er + h0);
            float4 xm = *(const float4*)(xr2 + h0);
            float4 qs = *(const float4*)(er + HH + h0);
            float4 xs = *(const float4*)(xr2 + HH + h0);
            float4 zv = *(const float4*)(zr + h0);
            float4 o;
            o.x = qm.x + __expf(0.5f * qs.x) * zv.x;
            o.y = qm.y + __expf(0.5f * qs.y) * zv.y;
            o.z = qm.z + __expf(0.5f * qs.z) * zv.z;
            o.w = qm.w + __expf(0.5f * qs.w) * zv.w;
            *(float4*)(out + OFF_OUT + (size_t)gt * HH + h0) = o;
            float dx, ds;
            dx = qm.x - xm.x; ssd += dx * dx;
            dx = qm.y - xm.y; ssd += dx * dx;
            dx = qm.z - xm.z; ssd += dx * dx;
            dx = qm.w - xm.w; ssd += dx * dx;
            ds = qs.x - xs.x; ssd += ds * ds;
            ds = qs.y - xs.y; ssd += ds * ds;
            ds = qs.z - xs.z; ssd += ds * ds;
            ds = qs.w - xs.w; ssd += ds * ds;
        }
        s_ssd[ltok][q] = ssd;
    }
    __syncthreads();

    if (tid < 64) {
        const int gt = blockIdx.x * 64 + tid;
        float tot = s_ssd[tid][0] + s_ssd[tid][1] + s_ssd[tid][2] + s_ssd[tid][3];
        float mean = tot * (1.0f / 128.0f);
        out[OFF_COM + gt] = mean;
        out[OFF_COD + gt] = mean;
    }
}

// ---------------------------------------------------------------------------
extern "C" void kernel_launch(void* const* d_in, const int* in_sizes, int n_in,
                              void* d_out, int out_size, void* d_ws, size_t ws_size,
                              hipStream_t stream) {
    const float* x   = (const float*)d_in[0];
    const float* emb = (const float*)d_in[1];
    const float* z   = (const float*)d_in[2];
    float* out = (float*)d_out;
    float4* stats = (float4*)d_ws;  // 2048 * 16 B = 32 KB

    hipLaunchKernelGGL(stats_kernel, dim3(KK / 256), dim3(256), 0, stream, emb, stats);
    hipLaunchKernelGGL(vq_kernel, dim3(NTOK / 64), dim3(256), 0, stream,
                       x, emb, z, stats, out);
}

// Round 2
// 373.204 us; speedup vs baseline: 1.0968x; 1.0968x over previous
//
#include <hip/hip_runtime.h>
#include <hip/hip_bf16.h>
#include <float.h>
#include <math.h>

// Problem constants (B=8, T=4096, D=128, K=2048)
#define NTOK 32768
#define DD 128
#define HH 64
#define KK 2048
#define NWAVE 8
#define BLOCK (NWAVE * 64)
#define CPW (KK / NWAVE)   // 256 codes per wave

// d_out flat layout (all float32):
#define OFF_OUT 0
#define OFF_IDS (NTOK * HH)            // 2097152
#define OFF_COM (OFF_IDS + NTOK)       // 2130176
#define OFF_COD (OFF_COM + NTOK)       // 2162944

// ---------------------------------------------------------------------------
// Kernel A: per-code stats. stats[k] = {0.5*sum(u), sum(mu^2), 1/(2*sum(exp u))}
// ---------------------------------------------------------------------------
__global__ __launch_bounds__(256) void stats_kernel(const float* __restrict__ emb,
                                                    float4* __restrict__ stats) {
    int k = blockIdx.x * blockDim.x + threadIdx.x;
    if (k >= KK) return;
    const float4* row = (const float4*)(emb + (size_t)k * DD);
    float b2 = 0.f, su = 0.f, se = 0.f;
#pragma unroll
    for (int j = 0; j < 16; ++j) {
        float4 m = row[j];
        b2 += m.x * m.x + m.y * m.y + m.z * m.z + m.w * m.w;
    }
#pragma unroll
    for (int j = 16; j < 32; ++j) {
        float4 u = row[j];
        su += u.x + u.y + u.z + u.w;
        se += __expf(u.x) + __expf(u.y) + __expf(u.z) + __expf(u.w);
    }
    stats[k] = make_float4(0.5f * su, b2, 1.0f / (2.0f * se), 0.f);
}

// ---------------------------------------------------------------------------
// fp64 exact distance (token-constant -sum(log sigma_i) dropped consistently)
// ---------------------------------------------------------------------------
__device__ double dist_fp64(const float* xr, const float* er) {
    double dot = 0.0, b2 = 0.0, le = 0.0, den = 0.0, c = 0.0;
    for (int h = 0; h < HH; ++h) {
        double mi = (double)xr[h];
        double me = (double)er[h];
        dot += mi * me;
        b2 += me * me;
        c += mi * mi;
        double ue = (double)er[HH + h];
        double ui = (double)xr[HH + h];
        le += ue;
        den += exp(ue);
        c += exp(ui);
    }
    return 0.5 * le + (c + b2 - 2.0 * dot) / (2.0 * den);
}

// ---------------------------------------------------------------------------
// Kernel B: main. 1 block = 64 tokens; lane = token; 8 waves split the codes.
// Inner loop unrolled x2 (two independent code streams) for memory-level
// parallelism; 512-thread blocks -> 2 blocks/CU, ~16 waves/CU resident.
// ---------------------------------------------------------------------------
__global__ __launch_bounds__(BLOCK) void vq_kernel(const float* __restrict__ x,
                                                   const float* __restrict__ emb,
                                                   const float* __restrict__ z,
                                                   const float4* __restrict__ stats,
                                                   float* __restrict__ out) {
    __shared__ float s_d1[NWAVE][64];
    __shared__ float s_d2[NWAVE][64];
    __shared__ int   s_i1[NWAVE][64];
    __shared__ int   s_i2[NWAVE][64];
    __shared__ int   s_bid[64];
    __shared__ float s_ssd[64][8];

    const int tid  = threadIdx.x;
    const int lane = tid & 63;
    const int wid  = __builtin_amdgcn_readfirstlane(tid >> 6);  // wave-uniform SGPR
    const int tok  = blockIdx.x * 64 + lane;

    // ---- load mu_i into registers, compute C = sum(mu^2) + sum(exp(x_h)) ----
    float mu[HH];
    float C = 0.f;
    const float4* xr = (const float4*)(x + (size_t)tok * DD);
#pragma unroll
    for (int j = 0; j < 16; ++j) {
        float4 m = xr[j];
        mu[4 * j + 0] = m.x;
        mu[4 * j + 1] = m.y;
        mu[4 * j + 2] = m.z;
        mu[4 * j + 3] = m.w;
        C += m.x * m.x + m.y * m.y + m.z * m.z + m.w * m.w;
    }
#pragma unroll
    for (int j = 16; j < 32; ++j) {
        float4 u = xr[j];
        C += __expf(u.x) + __expf(u.y) + __expf(u.z) + __expf(u.w);
    }

    // ---- scan this wave's code range, track top-2; 2 codes per iteration ----
    float d1 = FLT_MAX, d2 = FLT_MAX;
    int   i1 = 0, i2 = 0;
    const int kbase = wid * CPW;
    for (int kk = 0; kk < CPW; kk += 2) {
        const int ka = kbase + kk;                     // wave-uniform
        const int kb = ka + 1;
        const float4* cpa = (const float4*)(emb + (size_t)ka * DD);
        const float4* cpb = (const float4*)(emb + (size_t)kb * DD);
        const float4  sta = stats[ka];
        const float4  stb = stats[kb];
        float a0 = 0.f, a1 = 0.f, a2 = 0.f, a3 = 0.f;
        float b0 = 0.f, b1r = 0.f, b2r = 0.f, b3r = 0.f;
#pragma unroll
        for (int j = 0; j < 16; ++j) {
            float4 ea = cpa[j];
            float4 eb = cpb[j];
            a0  = fmaf(mu[4 * j + 0], ea.x, a0);
            a1  = fmaf(mu[4 * j + 1], ea.y, a1);
            a2  = fmaf(mu[4 * j + 2], ea.z, a2);
            a3  = fmaf(mu[4 * j + 3], ea.w, a3);
            b0  = fmaf(mu[4 * j + 0], eb.x, b0);
            b1r = fmaf(mu[4 * j + 1], eb.y, b1r);
            b2r = fmaf(mu[4 * j + 2], eb.z, b2r);
            b3r = fmaf(mu[4 * j + 3], eb.w, b3r);
        }
        const float dota = (a0 + a1) + (a2 + a3);
        const float dotb = (b0 + b1r) + (b2r + b3r);
        const float da = sta.x + (C + sta.y - 2.0f * dota) * sta.z;
        const float db = stb.x + (C + stb.y - 2.0f * dotb) * stb.z;
        if (da < d1)      { d2 = d1; i2 = i1; d1 = da; i1 = ka; }
        else if (da < d2) { d2 = da; i2 = ka; }
        if (db < d1)      { d2 = d1; i2 = i1; d1 = db; i1 = kb; }
        else if (db < d2) { d2 = db; i2 = kb; }
    }
    s_d1[wid][lane] = d1; s_i1[wid][lane] = i1;
    s_d2[wid][lane] = d2; s_i2[wid][lane] = i2;
    __syncthreads();

    // ---- combine across waves + near-tie fp64 rerank (threads 0..63) ----
    if (tid < 64) {
        float b1 = FLT_MAX, b2v = FLT_MAX;
        int   j1 = 0, j2 = 0;
        for (int w = 0; w < NWAVE; ++w) {
            float dA = s_d1[w][tid]; int iA = s_i1[w][tid];
            float dB = s_d2[w][tid]; int iB = s_i2[w][tid];
            if (dA < b1)      { b2v = b1; j2 = j1; b1 = dA; j1 = iA; }
            else if (dA < b2v){ b2v = dA; j2 = iA; }
            if (dB < b1)      { b2v = b1; j2 = j1; b1 = dB; j1 = iB; }
            else if (dB < b2v){ b2v = dB; j2 = iB; }
        }
        const int gtok = blockIdx.x * 64 + tid;
        if (b2v - b1 < 2e-4f * (1.0f + fabsf(b1))) {
            double e1 = dist_fp64(x + (size_t)gtok * DD, emb + (size_t)j1 * DD);
            double e2 = dist_fp64(x + (size_t)gtok * DD, emb + (size_t)j2 * DD);
            if (e2 < e1 || (e2 == e1 && j2 < j1)) j1 = j2;
        }
        s_bid[tid] = j1;
        out[OFF_IDS + gtok] = (float)j1;  // ids stored as float values
    }
    __syncthreads();

    // ---- epilogue: 8 threads per token, 8 out-dims (16 ssd-dims) each ----
    {
        const int ltok = tid >> 3;
        const int q    = tid & 7;
        const int gt   = blockIdx.x * 64 + ltok;
        const int code = s_bid[ltok];
        const float* er  = emb + (size_t)code * DD;
        const float* xr2 = x + (size_t)gt * DD;
        const float* zr  = z + (size_t)gt * HH;
        float ssd = 0.f;
#pragma unroll
        for (int j = 0; j < 2; ++j) {
            const int h0 = q * 8 + j * 4;
            float4 qm = *(const float4*)(er + h0);
            float4 xm = *(const float4*)(xr2 + h0);
            float4 qs = *(const float4*)(er + HH + h0);
            float4 xs = *(const float4*)(xr2 + HH + h0);
            float4 zv = *(const float4*)(zr + h0);
            float4 o;
            o.x = qm.x + __expf(0.5f * qs.x) * zv.x;
            o.y = qm.y + __expf(0.5f * qs.y) * zv.y;
            o.z = qm.z + __expf(0.5f * qs.z) * zv.z;
            o.w = qm.w + __expf(0.5f * qs.w) * zv.w;
            *(float4*)(out + OFF_OUT + (size_t)gt * HH + h0) = o;
            float dx, ds;
            dx = qm.x - xm.x; ssd += dx * dx;
            dx = qm.y - xm.y; ssd += dx * dx;
            dx = qm.z - xm.z; ssd += dx * dx;
            dx = qm.w - xm.w; ssd += dx * dx;
            ds = qs.x - xs.x; ssd += ds * ds;
            ds = qs.y - xs.y; ssd += ds * ds;
            ds = qs.z - xs.z; ssd += ds * ds;
            ds = qs.w - xs.w; ssd += ds * ds;
        }
        s_ssd[ltok][q] = ssd;
    }
    __syncthreads();

    if (tid < 64) {
        const int gt = blockIdx.x * 64 + tid;
        float tot = 0.f;
#pragma unroll
        for (int q = 0; q < 8; ++q) tot += s_ssd[tid][q];
        float mean = tot * (1.0f / 128.0f);
        out[OFF_COM + gt] = mean;
        out[OFF_COD + gt] = mean;
    }
}

// ---------------------------------------------------------------------------
extern "C" void kernel_launch(void* const* d_in, const int* in_sizes, int n_in,
                              void* d_out, int out_size, void* d_ws, size_t ws_size,
                              hipStream_t stream) {
    const float* x   = (const float*)d_in[0];
    const float* emb = (const float*)d_in[1];
    const float* z   = (const float*)d_in[2];
    float* out = (float*)d_out;
    float4* stats = (float4*)d_ws;  // 2048 * 16 B = 32 KB

    hipLaunchKernelGGL(stats_kernel, dim3(KK / 256), dim3(256), 0, stream, emb, stats);
    hipLaunchKernelGGL(vq_kernel, dim3(NTOK / 64), dim3(BLOCK), 0, stream,
                       x, emb, z, stats, out);
}

// Round 4
// 296.724 us; speedup vs baseline: 1.3796x; 1.2577x over previous
//
#include <hip/hip_runtime.h>
#include <hip/hip_bf16.h>
#include <float.h>
#include <math.h>

// Problem constants (B=8, T=4096, D=128, K=2048)
#define NTOK 32768
#define DD 128
#define HH 64
#define KK 2048

// d_out flat layout (all float32):
#define OFF_OUT 0
#define OFF_IDS (NTOK * HH)            // 2097152
#define OFF_COM (OFF_IDS + NTOK)       // 2130176
#define OFF_COD (OFF_COM + NTOK)       // 2162944

// ---- packed-K geometry: d(t,k) = <Apacked[t], Bpacked[k]> over KP dims ----
// logical 66 dims: [64 mu terms, C/stz term, const term], bf16 2-split packed
// as [AhiBhi(66) | AhiBlo(66) | AloBhi(66) | zeros], KP=224 = 7 x K32 MFMA.
#define KP 224
#define NSTEP 7
#define TILE_BYTES (16 * KP * 2)            // 7168 B per 16-row fragment tile
#define TILE_US (16 * KP)                   // 3584 ushorts
#define CH_TILES 4
#define CH_BYTES (CH_TILES * TILE_BYTES)    // 28672 B per code chunk (64 codes)
#define NCH (128 / CH_TILES)                // 32 chunks over 128 code tiles

// ws layout (bytes)
#define AP_BYTES ((size_t)NTOK * KP * 2)    // 14,680,064
#define BP_BYTES ((size_t)KK * KP * 2)      //    917,504
#define WS_AP  ((size_t)0)
#define WS_BP  (WS_AP + AP_BYTES)
#define WS_LE  (WS_BP + BP_BYTES)
#define WS_B2  (WS_LE + (size_t)KK * 8)
#define WS_DEN (WS_B2 + (size_t)KK * 8)
#define WS_NEED (WS_DEN + (size_t)KK * 8)   // ~15.65 MB

typedef short          s16x8 __attribute__((ext_vector_type(8)));
typedef unsigned short u16x8 __attribute__((ext_vector_type(8)));
typedef float          f32x4 __attribute__((ext_vector_type(4)));

// ---- bf16 helpers (RNE, matches HW) ----
static __device__ inline unsigned short f2bf(float v) {
    unsigned int u = __float_as_uint(v);
    unsigned int r = (u + 0x7FFFu + ((u >> 16) & 1u)) >> 16;
    return (unsigned short)r;
}
static __device__ inline float bf2f(unsigned short s) {
    return __uint_as_float(((unsigned int)s) << 16);
}
static __device__ inline unsigned short bf_hi(float v) { return f2bf(v); }
static __device__ inline unsigned short bf_lo(float v) {
    return f2bf(v - bf2f(f2bf(v)));
}

// ===========================================================================
// prep_a: per-token packed-A fragments. A logical = [mu(64), C, 1].
// A-side packing: kd<66 -> hi; 66..131 -> hi (pairs Blo); 132..197 -> lo.
// ===========================================================================
__global__ __launch_bounds__(256) void prep_a(const float* __restrict__ x,
                                              unsigned short* __restrict__ Ap) {
    int t = blockIdx.x * 256 + threadIdx.x;
    const float* row = x + (size_t)t * DD;
    float vals[66];
    float C = 0.f;
#pragma unroll
    for (int h = 0; h < HH; ++h) { float m = row[h]; vals[h] = m; C += m * m; }
#pragma unroll
    for (int h = HH; h < DD; ++h) C += __expf(row[h]);
    vals[64] = C; vals[65] = 1.0f;

    unsigned short* base = Ap + (size_t)(t >> 4) * TILE_US;
    const int col = t & 15;
#pragma unroll
    for (int s = 0; s < NSTEP; ++s) {
#pragma unroll
        for (int g = 0; g < 4; ++g) {
            u16x8 o;
#pragma unroll
            for (int j = 0; j < 8; ++j) {
                const int kd = s * 32 + g * 8 + j;
                unsigned short u = 0;
                if (kd < 66)       u = bf_hi(vals[kd]);
                else if (kd < 132) u = bf_hi(vals[kd - 66]);
                else if (kd < 198) u = bf_lo(vals[kd - 132]);
                o[j] = u;
            }
            *(u16x8*)(base + s * 512 + (g * 16 + col) * 8) = o;
        }
    }
}

// ===========================================================================
// prep_b: per-code packed-B fragments + fp64 stats for exact rescan.
// B logical = [-2*stz*mu_e(64), stz, stx+sty*stz].
// B-side packing: kd<66 -> hi; 66..131 -> lo; 132..197 -> hi.
// ===========================================================================
__global__ __launch_bounds__(256) void prep_b(const float* __restrict__ emb,
                                              unsigned short* __restrict__ Bp,
                                              double* __restrict__ Le,
                                              double* __restrict__ B2,
                                              double* __restrict__ Den) {
    int k = blockIdx.x * 256 + threadIdx.x;
    const float* row = emb + (size_t)k * DD;
    float me[64];
    float mu2 = 0.f, su = 0.f;
    double le = 0.0, b2 = 0.0, se = 0.0;
#pragma unroll
    for (int h = 0; h < HH; ++h) {
        float m = row[h]; me[h] = m; mu2 += m * m;
        b2 += (double)m * (double)m;
    }
#pragma unroll
    for (int h = HH; h < DD; ++h) {
        float u = row[h]; su += u; le += (double)u; se += exp((double)u);
    }
    const float stz = 1.0f / (2.0f * (float)se);
    float vals[66];
#pragma unroll
    for (int h = 0; h < HH; ++h) vals[h] = -2.0f * stz * me[h];
    vals[64] = stz;
    vals[65] = 0.5f * su + mu2 * stz;

    unsigned short* base = Bp + (size_t)(k >> 4) * TILE_US;
    const int col = k & 15;
#pragma unroll
    for (int s = 0; s < NSTEP; ++s) {
#pragma unroll
        for (int g = 0; g < 4; ++g) {
            u16x8 o;
#pragma unroll
            for (int j = 0; j < 8; ++j) {
                const int kd = s * 32 + g * 8 + j;
                unsigned short u = 0;
                if (kd < 66)       u = bf_hi(vals[kd]);
                else if (kd < 132) u = bf_lo(vals[kd - 66]);
                else if (kd < 198) u = bf_hi(vals[kd - 132]);
                o[j] = u;
            }
            *(u16x8*)(base + s * 512 + (g * 16 + col) * 8) = o;
        }
    }
    Le[k] = le; B2[k] = b2; Den[k] = se;
}

// ===========================================================================
// Main MFMA kernel. Block = 128 thr (2 waves), 64 tokens/block (32/wave via
// two A-sets). B streamed through double-buffered LDS chunks with async
// global_load_lds + counted vmcnt + raw barriers (T3/T4 pattern).
// ===========================================================================
#define TOP2UPD(dv, d1r, d2r, i1r) do { \
        bool _c1 = (dv) < (d1r); bool _c2 = (dv) < (d2r); \
        (d2r) = _c1 ? (d1r) : (_c2 ? (dv) : (d2r)); \
        (d1r) = _c1 ? (dv) : (d1r); \
        (i1r) = _c1 ? kcur : (i1r); \
    } while (0)

#define MERGE16(d1x, d2x, i1x) do { \
        _Pragma("unroll") \
        for (int _m = 1; _m <= 8; _m <<= 1) { \
            _Pragma("unroll") \
            for (int _r = 0; _r < 4; ++_r) { \
                float _od1 = __shfl_xor(d1x[_r], _m, 64); \
                float _od2 = __shfl_xor(d2x[_r], _m, 64); \
                int   _oi1 = __shfl_xor(i1x[_r], _m, 64); \
                bool _tk = (_od1 < d1x[_r]) || (_od1 == d1x[_r] && _oi1 < i1x[_r]); \
                float _hi = _tk ? d1x[_r] : _od1; \
                d1x[_r] = _tk ? _od1 : d1x[_r]; \
                i1x[_r] = _tk ? _oi1 : i1x[_r]; \
                d2x[_r] = fminf(_hi, fminf(d2x[_r], _od2)); \
            } \
        } \
    } while (0)

#if __has_builtin(__builtin_amdgcn_global_load_lds)
typedef __attribute__((address_space(1))) const unsigned int ga_u32;
typedef __attribute__((address_space(3))) unsigned int ls_u32;
#define STAGE(cc, bb) do { \
        const char* _s = bpc + (size_t)(cc) * CH_BYTES + wid * 1024 + lane * 16; \
        char* _d = smem + (bb) * CH_BYTES + wid * 1024; \
        _Pragma("unroll") \
        for (int _it = 0; _it < 14; ++_it) \
            __builtin_amdgcn_global_load_lds((ga_u32*)(_s + _it * 2048), \
                                             (ls_u32*)(_d + _it * 2048), 16, 0, 0); \
    } while (0)
#else
#define STAGE(cc, bb) do { \
        const char* _s = bpc + (size_t)(cc) * CH_BYTES; \
        _Pragma("unroll") \
        for (int _it = 0; _it < 14; ++_it) { \
            uint4 _v = *(const uint4*)(_s + _it * 2048 + tid * 16); \
            *(uint4*)(smem + (bb) * CH_BYTES + _it * 2048 + tid * 16) = _v; \
        } \
    } while (0)
#endif

__global__ __launch_bounds__(128) void vq_mfma(const float* __restrict__ x,
                                               const float* __restrict__ emb,
                                               const float* __restrict__ z,
                                               const unsigned short* __restrict__ Ap,
                                               const unsigned short* __restrict__ Bp,
                                               const double* __restrict__ Le,
                                               const double* __restrict__ B2,
                                               const double* __restrict__ Den,
                                               float* __restrict__ out) {
    __shared__ __align__(16) char smem[2 * CH_BYTES];   // 57344 B
    __shared__ int   s_bid[64];
    __shared__ int   s_flag[64];
    __shared__ float s_ssd[64][2];

    const int tid  = threadIdx.x;
    const int lane = tid & 63;
    const int wid  = __builtin_amdgcn_readfirstlane(tid >> 6);   // 0..1
    const char* bpc = (const char*)Bp;

    // ---- load both A fragment sets (2 token-tiles = 32 tokens / wave) ----
    s16x8 a0[NSTEP], a1[NSTEP];
    {
        const unsigned short* A0 = Ap + (size_t)(blockIdx.x * 4 + wid * 2) * TILE_US + lane * 8;
        const unsigned short* A1 = A0 + TILE_US;
#pragma unroll
        for (int s = 0; s < NSTEP; ++s) {
            a0[s] = *(const s16x8*)(A0 + s * 512);
            a1[s] = *(const s16x8*)(A1 + s * 512);
        }
    }
    asm volatile("s_waitcnt vmcnt(0)" ::: "memory");  // drain A before pipeline

    float d1a[4] = {FLT_MAX, FLT_MAX, FLT_MAX, FLT_MAX};
    float d2a[4] = {FLT_MAX, FLT_MAX, FLT_MAX, FLT_MAX};
    float d1b[4] = {FLT_MAX, FLT_MAX, FLT_MAX, FLT_MAX};
    float d2b[4] = {FLT_MAX, FLT_MAX, FLT_MAX, FLT_MAX};
    int   i1a[4] = {0, 0, 0, 0};
    int   i1b[4] = {0, 0, 0, 0};

    STAGE(0, 0);
    int kcur = lane & 15;
#pragma unroll 1
    for (int c = 0; c < NCH; ++c) {
        const int b = c & 1;
        if (c + 1 < NCH) {
            STAGE(c + 1, b ^ 1);
            asm volatile("s_waitcnt vmcnt(14)\ns_barrier" ::: "memory");
        } else {
            asm volatile("s_waitcnt vmcnt(0)\ns_barrier" ::: "memory");
        }
        const char* bufp = smem + b * CH_BYTES;
#pragma unroll
        for (int t = 0; t < CH_TILES; ++t) {
            f32x4 acc0 = {0.f, 0.f, 0.f, 0.f};
            f32x4 acc1 = {0.f, 0.f, 0.f, 0.f};
#pragma unroll
            for (int s = 0; s < NSTEP; ++s) {
                s16x8 bf = *(const s16x8*)(bufp + t * TILE_BYTES + s * 1024 + lane * 16);
                acc0 = __builtin_amdgcn_mfma_f32_16x16x32_bf16(a0[s], bf, acc0, 0, 0, 0);
                acc1 = __builtin_amdgcn_mfma_f32_16x16x32_bf16(a1[s], bf, acc1, 0, 0, 0);
            }
#pragma unroll
            for (int r = 0; r < 4; ++r) {
                TOP2UPD(acc0[r], d1a[r], d2a[r], i1a[r]);
                TOP2UPD(acc1[r], d1b[r], d2b[r], i1b[r]);
            }
            kcur += 16;
        }
        asm volatile("s_barrier" ::: "memory");   // protect buf before overwrite
    }

    // ---- merge top-2 across the 16 lanes sharing each row ----
    MERGE16(d1a, d2a, i1a);
    MERGE16(d1b, d2b, i1b);

    if ((lane & 15) == 0) {
#pragma unroll
        for (int r = 0; r < 4; ++r) {
            int ltok = (wid * 2 + 0) * 16 + ((lane >> 4) << 2) + r;
            s_bid[ltok]  = i1a[r];
            s_flag[ltok] = (d2a[r] - d1a[r]) < (6e-4f * (1.0f + fabsf(d1a[r]))) ? 1 : 0;
        }
#pragma unroll
        for (int r = 0; r < 4; ++r) {
            int ltok = (wid * 2 + 1) * 16 + ((lane >> 4) << 2) + r;
            s_bid[ltok]  = i1b[r];
            s_flag[ltok] = (d2b[r] - d1b[r]) < (6e-4f * (1.0f + fabsf(d1b[r]))) ? 1 : 0;
        }
    }

    // ---- exact fp64 rescan for flagged tokens (wave-parallel, rare) ----
    for (int rr = 0; rr < 32; ++rr) {
        const int ltok = wid * 32 + rr;
        if (s_flag[ltok]) {
            const int gt = blockIdx.x * 64 + ltok;
            const float* xr2 = x + (size_t)gt * DD;
            double C64 = 0.0;
            for (int h = 0; h < HH; ++h) { double m = xr2[h]; C64 += m * m; }
            for (int h = HH; h < DD; ++h) C64 += exp((double)xr2[h]);
            double best = 1e300; int bidx = 0;
            for (int c0 = 0; c0 < KK; c0 += 64) {
                const int cc = c0 + lane;
                const float* er = emb + (size_t)cc * DD;
                double dot = 0.0;
                for (int h = 0; h < HH; ++h) dot += (double)xr2[h] * (double)er[h];
                double dv = 0.5 * Le[cc] + (C64 + B2[cc] - 2.0 * dot) / (2.0 * Den[cc]);
                if (dv < best) { best = dv; bidx = cc; }
            }
            for (int m = 32; m >= 1; m >>= 1) {
                double ob = __shfl_xor(best, m, 64);
                int    oi = __shfl_xor(bidx, m, 64);
                if (ob < best || (ob == best && oi < bidx)) { best = ob; bidx = oi; }
            }
            if (lane == 0) s_bid[ltok] = bidx;
        }
    }
    __syncthreads();

    // ---- epilogue: 2 threads per token, 32 out-dims each ----
    {
        const int ltok = tid >> 1;
        const int half = tid & 1;
        const int gt   = blockIdx.x * 64 + ltok;
        const int code = s_bid[ltok];
        const float* er  = emb + (size_t)code * DD;
        const float* xr2 = x + (size_t)gt * DD;
        const float* zr  = z + (size_t)gt * HH;
        float ssd = 0.f;
#pragma unroll
        for (int j = 0; j < 8; ++j) {
            const int h0 = half * 32 + j * 4;
            float4 qm = *(const float4*)(er + h0);
            float4 xm = *(const float4*)(xr2 + h0);
            float4 qs = *(const float4*)(er + HH + h0);
            float4 xs = *(const float4*)(xr2 + HH + h0);
            float4 zv = *(const float4*)(zr + h0);
            float4 o;
            o.x = qm.x + __expf(0.5f * qs.x) * zv.x;
            o.y = qm.y + __expf(0.5f * qs.y) * zv.y;
            o.z = qm.z + __expf(0.5f * qs.z) * zv.z;
            o.w = qm.w + __expf(0.5f * qs.w) * zv.w;
            *(float4*)(out + OFF_OUT + (size_t)gt * HH + h0) = o;
            float dx, ds;
            dx = qm.x - xm.x; ssd += dx * dx;
            dx = qm.y - xm.y; ssd += dx * dx;
            dx = qm.z - xm.z; ssd += dx * dx;
            dx = qm.w - xm.w; ssd += dx * dx;
            ds = qs.x - xs.x; ssd += ds * ds;
            ds = qs.y - xs.y; ssd += ds * ds;
            ds = qs.z - xs.z; ssd += ds * ds;
            ds = qs.w - xs.w; ssd += ds * ds;
        }
        s_ssd[ltok][half] = ssd;
    }
    __syncthreads();

    if (tid < 64) {
        const int gt = blockIdx.x * 64 + tid;
        float mean = (s_ssd[tid][0] + s_ssd[tid][1]) * (1.0f / 128.0f);
        out[OFF_IDS + gt] = (float)s_bid[tid];
        out[OFF_COM + gt] = mean;
        out[OFF_COD + gt] = mean;
    }
}

// ===========================================================================
// Fallback path (round-2 VALU kernel) if ws is too small for packed buffers.
// ===========================================================================
__global__ __launch_bounds__(256) void stats_kernel(const float* __restrict__ emb,
                                                    float4* __restrict__ stats) {
    int k = blockIdx.x * blockDim.x + threadIdx.x;
    if (k >= KK) return;
    const float4* row = (const float4*)(emb + (size_t)k * DD);
    float b2 = 0.f, su = 0.f, se = 0.f;
#pragma unroll
    for (int j = 0; j < 16; ++j) {
        float4 m = row[j];
        b2 += m.x * m.x + m.y * m.y + m.z * m.z + m.w * m.w;
    }
#pragma unroll
    for (int j = 16; j < 32; ++j) {
        float4 u = row[j];
        su += u.x + u.y + u.z + u.w;
        se += __expf(u.x) + __expf(u.y) + __expf(u.z) + __expf(u.w);
    }
    stats[k] = make_float4(0.5f * su, b2, 1.0f / (2.0f * se), 0.f);
}

__device__ double dist_fp64(const float* xr, const float* er) {
    double dot = 0.0, b2 = 0.0, le = 0.0, den = 0.0, c = 0.0;
    for (int h = 0; h < HH; ++h) {
        double mi = (double)xr[h];
        double me = (double)er[h];
        dot += mi * me; b2 += me * me; c += mi * mi;
        le += (double)er[HH + h];
        den += exp((double)er[HH + h]);
        c += exp((double)xr[HH + h]);
    }
    return 0.5 * le + (c + b2 - 2.0 * dot) / (2.0 * den);
}

#define FB_NWAVE 8
__global__ __launch_bounds__(512) void vq_fb(const float* __restrict__ x,
                                             const float* __restrict__ emb,
                                             const float* __restrict__ z,
                                             const float4* __restrict__ stats,
                                             float* __restrict__ out) {
    __shared__ float s_d1[FB_NWAVE][64];
    __shared__ float s_d2[FB_NWAVE][64];
    __shared__ int   s_i1[FB_NWAVE][64];
    __shared__ int   s_i2[FB_NWAVE][64];
    __shared__ int   s_bid[64];
    __shared__ float s_ssd[64][8];

    const int tid  = threadIdx.x;
    const int lane = tid & 63;
    const int wid  = __builtin_amdgcn_readfirstlane(tid >> 6);
    const int tok  = blockIdx.x * 64 + lane;

    float mu[HH]; float C = 0.f;
    const float4* xr = (const float4*)(x + (size_t)tok * DD);
#pragma unroll
    for (int j = 0; j < 16; ++j) {
        float4 m = xr[j];
        mu[4*j+0] = m.x; mu[4*j+1] = m.y; mu[4*j+2] = m.z; mu[4*j+3] = m.w;
        C += m.x*m.x + m.y*m.y + m.z*m.z + m.w*m.w;
    }
#pragma unroll
    for (int j = 16; j < 32; ++j) {
        float4 u = xr[j];
        C += __expf(u.x) + __expf(u.y) + __expf(u.z) + __expf(u.w);
    }
    float d1 = FLT_MAX, d2 = FLT_MAX; int i1 = 0, i2 = 0;
    const int kbase = wid * (KK / FB_NWAVE);
    for (int kk = 0; kk < KK / FB_NWAVE; kk += 2) {
        const int ka = kbase + kk, kb = ka + 1;
        const float4* cpa = (const float4*)(emb + (size_t)ka * DD);
        const float4* cpb = (const float4*)(emb + (size_t)kb * DD);
        const float4 sta = stats[ka], stb = stats[kb];
        float a0=0,a1=0,a2=0,a3=0,b0=0,b1r=0,b2r=0,b3r=0;
#pragma unroll
        for (int j = 0; j < 16; ++j) {
            float4 ea = cpa[j], eb = cpb[j];
            a0 = fmaf(mu[4*j+0], ea.x, a0); a1 = fmaf(mu[4*j+1], ea.y, a1);
            a2 = fmaf(mu[4*j+2], ea.z, a2); a3 = fmaf(mu[4*j+3], ea.w, a3);
            b0 = fmaf(mu[4*j+0], eb.x, b0); b1r = fmaf(mu[4*j+1], eb.y, b1r);
            b2r = fmaf(mu[4*j+2], eb.z, b2r); b3r = fmaf(mu[4*j+3], eb.w, b3r);
        }
        float da = sta.x + (C + sta.y - 2.f*((a0+a1)+(a2+a3))) * sta.z;
        float db = stb.x + (C + stb.y - 2.f*((b0+b1r)+(b2r+b3r))) * stb.z;
        if (da < d1) { d2=d1; i2=i1; d1=da; i1=ka; } else if (da < d2) { d2=da; i2=ka; }
        if (db < d1) { d2=d1; i2=i1; d1=db; i1=kb; } else if (db < d2) { d2=db; i2=kb; }
    }
    s_d1[wid][lane]=d1; s_i1[wid][lane]=i1; s_d2[wid][lane]=d2; s_i2[wid][lane]=i2;
    __syncthreads();
    if (tid < 64) {
        float b1 = FLT_MAX, b2v = FLT_MAX; int j1 = 0, j2 = 0;
        for (int w = 0; w < FB_NWAVE; ++w) {
            float dA = s_d1[w][tid]; int iA = s_i1[w][tid];
            float dB = s_d2[w][tid]; int iB = s_i2[w][tid];
            if (dA < b1) { b2v=b1; j2=j1; b1=dA; j1=iA; } else if (dA < b2v) { b2v=dA; j2=iA; }
            if (dB < b1) { b2v=b1; j2=j1; b1=dB; j1=iB; } else if (dB < b2v) { b2v=dB; j2=iB; }
        }
        const int gtok = blockIdx.x * 64 + tid;
        if (b2v - b1 < 2e-4f * (1.0f + fabsf(b1))) {
            double e1 = dist_fp64(x + (size_t)gtok*DD, emb + (size_t)j1*DD);
            double e2 = dist_fp64(x + (size_t)gtok*DD, emb + (size_t)j2*DD);
            if (e2 < e1 || (e2 == e1 && j2 < j1)) j1 = j2;
        }
        s_bid[tid] = j1;
        out[OFF_IDS + gtok] = (float)j1;
    }
    __syncthreads();
    {
        const int ltok = tid >> 3, q = tid & 7;
        const int gt = blockIdx.x * 64 + ltok;
        const int code = s_bid[ltok];
        const float* er = emb + (size_t)code * DD;
        const float* xr2 = x + (size_t)gt * DD;
        const float* zr = z + (size_t)gt * HH;
        float ssd = 0.f;
#pragma unroll
        for (int j = 0; j < 2; ++j) {
            const int h0 = q * 8 + j * 4;
            float4 qm = *(const float4*)(er + h0);
            float4 xm = *(const float4*)(xr2 + h0);
            float4 qs = *(const float4*)(er + HH + h0);
            float4 xs = *(const float4*)(xr2 + HH + h0);
            float4 zv = *(const float4*)(zr + h0);
            float4 o;
            o.x = qm.x + __expf(0.5f*qs.x)*zv.x; o.y = qm.y + __expf(0.5f*qs.y)*zv.y;
            o.z = qm.z + __expf(0.5f*qs.z)*zv.z; o.w = qm.w + __expf(0.5f*qs.w)*zv.w;
            *(float4*)(out + OFF_OUT + (size_t)gt * HH + h0) = o;
            float dx, ds;
            dx=qm.x-xm.x; ssd+=dx*dx; dx=qm.y-xm.y; ssd+=dx*dx;
            dx=qm.z-xm.z; ssd+=dx*dx; dx=qm.w-xm.w; ssd+=dx*dx;
            ds=qs.x-xs.x; ssd+=ds*ds; ds=qs.y-xs.y; ssd+=ds*ds;
            ds=qs.z-xs.z; ssd+=ds*ds; ds=qs.w-xs.w; ssd+=ds*ds;
        }
        s_ssd[ltok][q] = ssd;
    }
    __syncthreads();
    if (tid < 64) {
        const int gt = blockIdx.x * 64 + tid;
        float tot = 0.f;
#pragma unroll
        for (int q = 0; q < 8; ++q) tot += s_ssd[tid][q];
        float mean = tot * (1.0f / 128.0f);
        out[OFF_COM + gt] = mean; out[OFF_COD + gt] = mean;
    }
}

// ---------------------------------------------------------------------------
extern "C" void kernel_launch(void* const* d_in, const int* in_sizes, int n_in,
                              void* d_out, int out_size, void* d_ws, size_t ws_size,
                              hipStream_t stream) {
    const float* x   = (const float*)d_in[0];
    const float* emb = (const float*)d_in[1];
    const float* z   = (const float*)d_in[2];
    float* out = (float*)d_out;

    if (ws_size >= WS_NEED) {
        unsigned short* Ap = (unsigned short*)((char*)d_ws + WS_AP);
        unsigned short* Bp = (unsigned short*)((char*)d_ws + WS_BP);
        double* Le  = (double*)((char*)d_ws + WS_LE);
        double* B2  = (double*)((char*)d_ws + WS_B2);
        double* Den = (double*)((char*)d_ws + WS_DEN);
        hipLaunchKernelGGL(prep_a, dim3(NTOK / 256), dim3(256), 0, stream, x, Ap);
        hipLaunchKernelGGL(prep_b, dim3(KK / 256), dim3(256), 0, stream, emb, Bp, Le, B2, Den);
        hipLaunchKernelGGL(vq_mfma, dim3(NTOK / 64), dim3(128), 0, stream,
                           x, emb, z, Ap, Bp, Le, B2, Den, out);
    } else {
        float4* stats = (float4*)d_ws;
        hipLaunchKernelGGL(stats_kernel, dim3(KK / 256), dim3(256), 0, stream, emb, stats);
        hipLaunchKernelGGL(vq_fb, dim3(NTOK / 64), dim3(512), 0, stream,
                           x, emb, z, stats, out);
    }
}

// Round 8
// 149.373 us; speedup vs baseline: 2.7404x; 1.9865x over previous
//
#include <hip/hip_runtime.h>
#include <float.h>
#include <math.h>

// Problem constants (B=8, T=4096, D=128, K=2048)
#define NTOK 32768
#define DD 128
#define HH 64
#define KK 2048
#define NSLICE 4
#define TG_COUNT (NTOK / 64)          // 512 token groups
#define NCHUNK 32                     // 32 one-tile chunks per wave = FULL slice (512 codes)

// d_out flat layout (all float32):
#define OFF_OUT 0
#define OFF_IDS (NTOK * HH)
#define OFF_COM (OFF_IDS + NTOK)
#define OFF_COD (OFF_COM + NTOK)

// ws layout (bytes)
#define WS_BP   ((size_t)0)                    // B tiles: 128 tiles * 4096 = 524288
#define WS_ST   (WS_BP + 524288)               // stats4: 2048*16 = 32768
#define WS_C    (WS_ST + 32768)                // C per token: 32768*4 = 131072
#define WS_CAND (WS_C + 131072)                // cand: NSLICE*NTOK*16 = 2097152
#define WS_LE   (WS_CAND + 2097152)
#define WS_B2   (WS_LE + (size_t)KK * 8)
#define WS_DEN  (WS_B2 + (size_t)KK * 8)
#define WS_NEED (WS_DEN + (size_t)KK * 8)      // ~2.83 MB

typedef short s16x8 __attribute__((ext_vector_type(8)));
typedef float f32x4 __attribute__((ext_vector_type(4)));

// ---- bf16 helpers (RNE) ----
static __device__ inline unsigned short f2bf(float v) {
    unsigned int u = __float_as_uint(v);
    unsigned int r = (u + 0x7FFFu + ((u >> 16) & 1u)) >> 16;
    return (unsigned short)r;
}
static __device__ inline float bf2f(unsigned short s) {
    return __uint_as_float(((unsigned int)s) << 16);
}
static __device__ inline unsigned short bf_hi(float v) { return f2bf(v); }
static __device__ inline unsigned short bf_lo(float v) { return f2bf(v - bf2f(f2bf(v))); }

// ===========================================================================
// prep_c: C[t] = sum(mu_i^2) + sum(exp(x_sig)) per token. Coalesced.
// ===========================================================================
__global__ __launch_bounds__(256) void prep_c(const float* __restrict__ x,
                                              float* __restrict__ Cg) {
    __shared__ float p_lds[64 * 33];
    const int tid = threadIdx.x;
    const float4* xb = (const float4*)x + (size_t)blockIdx.x * 2048;
#pragma unroll
    for (int i = 0; i < 8; ++i) {
        int fid = i * 256 + tid;
        float4 v = xb[fid];
        int r = fid >> 5, c = fid & 31;
        float p;
        if (c < 16) p = v.x * v.x + v.y * v.y + v.z * v.z + v.w * v.w;
        else        p = __expf(v.x) + __expf(v.y) + __expf(v.z) + __expf(v.w);
        p_lds[r * 33 + c] = p;
    }
    __syncthreads();
    if (tid < 64) {
        float s = 0.f;
#pragma unroll
        for (int c = 0; c < 32; ++c) s += p_lds[tid * 33 + c];
        Cg[blockIdx.x * 64 + tid] = s;
    }
}

// ===========================================================================
// prep_b: B tiles (4 planes: muHi[0:32], muHi[32:64], muLo[0:32], muLo[32:64])
// in MFMA fragment order + fp32 stats (0.5*le, b2, stz) + fp64 stats.
// ===========================================================================
__global__ __launch_bounds__(256) void prep_b(const float* __restrict__ emb,
                                              unsigned short* __restrict__ Bp,
                                              float4* __restrict__ st4,
                                              double* __restrict__ Le,
                                              double* __restrict__ B2,
                                              double* __restrict__ Den) {
    int k = blockIdx.x * 256 + threadIdx.x;   // grid = KK/256
    const float* row = emb + (size_t)k * DD;
    float me[64];
    double le = 0.0, b2 = 0.0, se = 0.0;
#pragma unroll
    for (int h = 0; h < HH; ++h) {
        float m = row[h]; me[h] = m;
        b2 += (double)m * (double)m;
    }
#pragma unroll
    for (int h = 0; h < HH; ++h) {
        float u = row[HH + h];
        le += (double)u; se += exp((double)u);
    }
    const float stz = (float)(1.0 / (2.0 * se));

    unsigned short* tb = Bp + (size_t)(k >> 4) * 2048;  // ushort units per 4KB tile
    const int col = k & 15;
#pragma unroll
    for (int g = 0; g < 4; ++g) {
        s16x8 o0, o1, o2, o3;
#pragma unroll
        for (int j = 0; j < 8; ++j) {
            int h = g * 8 + j;
            o0[j] = (short)bf_hi(me[h]);
            o1[j] = (short)bf_hi(me[32 + h]);
            o2[j] = (short)bf_lo(me[h]);
            o3[j] = (short)bf_lo(me[32 + h]);
        }
        int base = (g * 16 + col) * 8;
        *(s16x8*)(tb + 0 * 512 + base) = o0;
        *(s16x8*)(tb + 1 * 512 + base) = o1;
        *(s16x8*)(tb + 2 * 512 + base) = o2;
        *(s16x8*)(tb + 3 * 512 + base) = o3;
    }
    st4[k] = make_float4(0.5f * (float)le, (float)b2, stz, 0.f);
    Le[k] = le; B2[k] = b2; Den[k] = se;
}

// ===========================================================================
// vq_mfma: 2048 blocks (512 token-groups x 4 K-slices), 128 thr (2 waves).
// BOTH waves scan the FULL slice (512 codes); wave = 32 tokens (2 A-tiles).
// B fragments loaded DIRECTLY from global (L2-resident) into registers with
// a 2-set software prefetch. No LDS, no inline-asm waitcnt ledger.
// ===========================================================================
#define TOP2(dv, kg, D1, D2, I1, I2) do {                  \
        bool _c1 = (dv) < (D1); bool _c2 = (dv) < (D2);    \
        (D2) = _c1 ? (D1) : (_c2 ? (dv) : (D2));           \
        (I2) = _c1 ? (I1) : (_c2 ? (kg) : (I2));           \
        (D1) = _c1 ? (dv) : (D1);                          \
        (I1) = _c1 ? (kg) : (I1);                          \
    } while (0)

#define LOADB(kt, B0, B1, B2v, B3v, ST) do {                       \
        const char* _p = bpc + (size_t)(kt) * 4096 + lane * 16;    \
        B0  = *(const s16x8*)(_p + 0 * 1024);                      \
        B1  = *(const s16x8*)(_p + 1 * 1024);                      \
        B2v = *(const s16x8*)(_p + 2 * 1024);                      \
        B3v = *(const s16x8*)(_p + 3 * 1024);                      \
        ST  = *(const f32x4*)(st4 + (size_t)(kt) * 16 + colv);     \
    } while (0)

#define COMPUTE(B0, B1, B2v, B3v, ST, KG) do {                                       \
        f32x4 acc0 = {0.f, 0.f, 0.f, 0.f};                                           \
        f32x4 acc1 = {0.f, 0.f, 0.f, 0.f};                                           \
        acc0 = __builtin_amdgcn_mfma_f32_16x16x32_bf16(aH00, B0,  acc0, 0, 0, 0);    \
        acc1 = __builtin_amdgcn_mfma_f32_16x16x32_bf16(aH10, B0,  acc1, 0, 0, 0);    \
        acc0 = __builtin_amdgcn_mfma_f32_16x16x32_bf16(aH01, B1,  acc0, 0, 0, 0);    \
        acc1 = __builtin_amdgcn_mfma_f32_16x16x32_bf16(aH11, B1,  acc1, 0, 0, 0);    \
        acc0 = __builtin_amdgcn_mfma_f32_16x16x32_bf16(aH00, B2v, acc0, 0, 0, 0);    \
        acc1 = __builtin_amdgcn_mfma_f32_16x16x32_bf16(aH10, B2v, acc1, 0, 0, 0);    \
        acc0 = __builtin_amdgcn_mfma_f32_16x16x32_bf16(aH01, B3v, acc0, 0, 0, 0);    \
        acc1 = __builtin_amdgcn_mfma_f32_16x16x32_bf16(aH11, B3v, acc1, 0, 0, 0);    \
        acc0 = __builtin_amdgcn_mfma_f32_16x16x32_bf16(aL00, B0,  acc0, 0, 0, 0);    \
        acc1 = __builtin_amdgcn_mfma_f32_16x16x32_bf16(aL10, B0,  acc1, 0, 0, 0);    \
        acc0 = __builtin_amdgcn_mfma_f32_16x16x32_bf16(aL01, B1,  acc0, 0, 0, 0);    \
        acc1 = __builtin_amdgcn_mfma_f32_16x16x32_bf16(aL11, B1,  acc1, 0, 0, 0);    \
        const float g3  = -2.f * ST[2];                                              \
        const float f1v = ST[0];                                                     \
        _Pragma("unroll")                                                            \
        for (int r = 0; r < 4; ++r) {                                                \
            float b0v = fmaf(c40[r] + ST[1], ST[2], f1v);                            \
            float dA  = fmaf(acc0[r], g3, b0v);                                      \
            TOP2(dA, (KG), d1[0][r], d2[0][r], i1[0][r], i2[0][r]);                  \
            float b1v = fmaf(c41[r] + ST[1], ST[2], f1v);                            \
            float dB  = fmaf(acc1[r], g3, b1v);                                      \
            TOP2(dB, (KG), d1[1][r], d2[1][r], i1[1][r], i2[1][r]);                  \
        }                                                                            \
    } while (0)

static __device__ inline void mk_frag(float4 a, float4 b, s16x8& hi, s16x8& lo) {
    float f[8] = {a.x, a.y, a.z, a.w, b.x, b.y, b.z, b.w};
#pragma unroll
    for (int j = 0; j < 8; ++j) {
        hi[j] = (short)bf_hi(f[j]);
        lo[j] = (short)bf_lo(f[j]);
    }
}

__global__ __launch_bounds__(128) void vq_mfma(const float* __restrict__ x,
                                               const unsigned short* __restrict__ Bp,
                                               const float4* __restrict__ st4,
                                               const float* __restrict__ Cg,
                                               float4* __restrict__ cand) {
    const int tid  = threadIdx.x;
    const int lane = tid & 63;
    const int wid  = tid >> 6;                 // 0..1 (token half only!)
    const int tg    = blockIdx.x & (TG_COUNT - 1);
    const int slice = blockIdx.x >> 9;
    const int grp  = lane >> 4;
    const int colv = lane & 15;
    const char* bpc = (const char*)Bp;

    // ---- build A fragments (hi/lo) + per-row C, direct from global ----
    s16x8 aH00, aH01, aL00, aL01;    // set 0: tokens [0..15] of this wave's 32
    s16x8 aH10, aH11, aL10, aL11;    // set 1: tokens [16..31]
    f32x4 c40, c41;
    {
        const int hb = grp * 8;
        const float* xr0 = x + (size_t)(tg * 64 + wid * 32 + colv) * DD;
        const float* xr1 = xr0 + 16 * DD;
        float4 v0 = *(const float4*)(xr0 + hb);
        float4 v1 = *(const float4*)(xr0 + hb + 4);
        float4 v2 = *(const float4*)(xr0 + hb + 32);
        float4 v3 = *(const float4*)(xr0 + hb + 36);
        mk_frag(v0, v1, aH00, aL00);
        mk_frag(v2, v3, aH01, aL01);
        v0 = *(const float4*)(xr1 + hb);
        v1 = *(const float4*)(xr1 + hb + 4);
        v2 = *(const float4*)(xr1 + hb + 32);
        v3 = *(const float4*)(xr1 + hb + 36);
        mk_frag(v0, v1, aH10, aL10);
        mk_frag(v2, v3, aH11, aL11);
        c40 = *(const f32x4*)(Cg + tg * 64 + wid * 32 + grp * 4);
        c41 = *(const f32x4*)(Cg + tg * 64 + wid * 32 + 16 + grp * 4);
    }

    float d1[2][4], d2[2][4];
    int   i1[2][4], i2[2][4];
#pragma unroll
    for (int s = 0; s < 2; ++s)
#pragma unroll
        for (int r = 0; r < 4; ++r) {
            d1[s][r] = FLT_MAX; d2[s][r] = FLT_MAX; i1[s][r] = 0; i2[s][r] = 0;
        }

    // FULL slice for both waves: codes [slice*512, slice*512+512)
    const int kt0 = slice * 32;
    const int kg0 = slice * 512 + colv;

    s16x8 pb0, pb1, pb2, pb3; f32x4 pst;
    s16x8 qb0, qb1, qb2, qb3; f32x4 qst;
    LOADB(kt0, pb0, pb1, pb2, pb3, pst);
#pragma unroll 1
    for (int c = 0; c < NCHUNK; c += 2) {
        LOADB(kt0 + c + 1, qb0, qb1, qb2, qb3, qst);          // prefetch odd chunk
        COMPUTE(pb0, pb1, pb2, pb3, pst, kg0 + c * 16);
        if (c + 2 < NCHUNK)
            LOADB(kt0 + c + 2, pb0, pb1, pb2, pb3, pst);      // prefetch next even
        COMPUTE(qb0, qb1, qb2, qb3, qst, kg0 + (c + 1) * 16);
    }

    // ---- merge top-2 across the 16 lanes of each row group ----
#pragma unroll
    for (int m = 1; m <= 8; m <<= 1) {
#pragma unroll
        for (int s = 0; s < 2; ++s)
#pragma unroll
            for (int r = 0; r < 4; ++r) {
                float od1 = __shfl_xor(d1[s][r], m, 64);
                int   oi1 = __shfl_xor(i1[s][r], m, 64);
                float od2 = __shfl_xor(d2[s][r], m, 64);
                int   oi2 = __shfl_xor(i2[s][r], m, 64);
                bool take = (od1 < d1[s][r]) || (od1 == d1[s][r] && oi1 < i1[s][r]);
                float rA = take ? d1[s][r] : od1;
                int  riA = take ? i1[s][r] : oi1;
                float rB = take ? od2 : d2[s][r];
                int  riB = take ? oi2 : i2[s][r];
                if (take) { d1[s][r] = od1; i1[s][r] = oi1; }
                bool t2 = (rA < rB) || (rA == rB && riA < riB);
                d2[s][r] = t2 ? rA : rB;
                i2[s][r] = t2 ? riA : riB;
            }
    }

    if (colv == 0) {
#pragma unroll
        for (int s = 0; s < 2; ++s)
#pragma unroll
            for (int r = 0; r < 4; ++r) {
                int tl = wid * 32 + s * 16 + grp * 4 + r;
                float4 o;
                o.x = d1[s][r]; o.y = d2[s][r];
                o.z = __int_as_float(i1[s][r]); o.w = __int_as_float(i2[s][r]);
                cand[(size_t)slice * NTOK + tg * 64 + tl] = o;
            }
    }
}

// ===========================================================================
// finalize: fp64-rerank ALL 8 slice candidates (lex-min on (d, idx)), with
// full-fp64-C refinement for ultra-near ties; then epilogue.
// ===========================================================================
static __device__ double dist64(const float* xr, const float* emb, int k, double Cv,
                                const double* Le, const double* B2, const double* Den) {
    const float4* er = (const float4*)(emb + (size_t)k * DD);
    const float4* xv = (const float4*)xr;
    double s0 = 0.0, s1 = 0.0;
#pragma unroll
    for (int j = 0; j < 16; ++j) {
        float4 e = er[j]; float4 xx = xv[j];
        s0 += (double)xx.x * (double)e.x + (double)xx.z * (double)e.z;
        s1 += (double)xx.y * (double)e.y + (double)xx.w * (double)e.w;
    }
    return 0.5 * Le[k] + (Cv + B2[k] - 2.0 * (s0 + s1)) / (2.0 * Den[k]);
}

__global__ __launch_bounds__(256) void finalize(const float* __restrict__ x,
                                                const float* __restrict__ emb,
                                                const float* __restrict__ z,
                                                const float4* __restrict__ cand,
                                                const float* __restrict__ Cg,
                                                const double* __restrict__ Le,
                                                const double* __restrict__ B2,
                                                const double* __restrict__ Den,
                                                float* __restrict__ out) {
    __shared__ int   s_bid[64];
    __shared__ float s_ssd[64][4];
    const int tid = threadIdx.x;
    const int tb  = blockIdx.x * 64;

    if (tid < 64) {
        const int gt = tb + tid;
        const float* xr = x + (size_t)gt * DD;
        double Cv = (double)Cg[gt];
        double bd = 1e300, bd2 = 1e300;
        int    bi = 0,     bi2 = 0;
#pragma unroll
        for (int s = 0; s < NSLICE; ++s) {
            float4 cd = cand[(size_t)s * NTOK + gt];
            int ka = __float_as_int(cd.z);
            int kb = __float_as_int(cd.w);
            double da = dist64(xr, emb, ka, Cv, Le, B2, Den);
            double db = dist64(xr, emb, kb, Cv, Le, B2, Den);
            if ((da < bd) || (da == bd && ka < bi)) {
                bd2 = bd; bi2 = bi; bd = da; bi = ka;
            } else if ((da < bd2) || (da == bd2 && ka < bi2)) {
                bd2 = da; bi2 = ka;
            }
            if ((db < bd) || (db == bd && kb < bi)) {
                bd2 = bd; bi2 = bi; bd = db; bi = kb;
            } else if ((db < bd2) || (db == bd2 && kb < bi2)) {
                bd2 = db; bi2 = kb;
            }
        }
        if (bd2 - bd < 1e-5 * (1.0 + fabs(bd))) {
            double C64 = 0.0;
            for (int h = 0; h < HH; ++h) { double m = (double)xr[h]; C64 += m * m; }
            for (int h = HH; h < DD; ++h) C64 += exp((double)xr[h]);
            double da = dist64(xr, emb, bi,  C64, Le, B2, Den);
            double db = dist64(xr, emb, bi2, C64, Le, B2, Den);
            if (db < da || (db == da && bi2 < bi)) bi = bi2;
        }
        s_bid[tid] = bi;
        out[OFF_IDS + gt] = (float)bi;
    }
    __syncthreads();

    // epilogue: 4 threads per token, 16 out-dims each
    {
        const int ltok = tid >> 2;
        const int q    = tid & 3;
        const int gt   = tb + ltok;
        const int code = s_bid[ltok];
        const float* er  = emb + (size_t)code * DD;
        const float* xr2 = x + (size_t)gt * DD;
        const float* zr  = z + (size_t)gt * HH;
        float ssd = 0.f;
#pragma unroll
        for (int j = 0; j < 4; ++j) {
            const int h0 = q * 16 + j * 4;
            float4 qm = *(const float4*)(er + h0);
            float4 xm = *(const float4*)(xr2 + h0);
            float4 qs = *(const float4*)(er + HH + h0);
            float4 xs = *(const float4*)(xr2 + HH + h0);
            float4 zv = *(const float4*)(zr + h0);
            float4 o;
            o.x = qm.x + __expf(0.5f * qs.x) * zv.x;
            o.y = qm.y + __expf(0.5f * qs.y) * zv.y;
            o.z = qm.z + __expf(0.5f * qs.z) * zv.z;
            o.w = qm.w + __expf(0.5f * qs.w) * zv.w;
            *(float4*)(out + OFF_OUT + (size_t)gt * HH + h0) = o;
            float dx, ds;
            dx = qm.x - xm.x; ssd += dx * dx;
            dx = qm.y - xm.y; ssd += dx * dx;
            dx = qm.z - xm.z; ssd += dx * dx;
            dx = qm.w - xm.w; ssd += dx * dx;
            ds = qs.x - xs.x; ssd += ds * ds;
            ds = qs.y - xs.y; ssd += ds * ds;
            ds = qs.z - xs.z; ssd += ds * ds;
            ds = qs.w - xs.w; ssd += ds * ds;
        }
        s_ssd[ltok][q] = ssd;
    }
    __syncthreads();

    if (tid < 64) {
        const int gt = tb + tid;
        float tot = s_ssd[tid][0] + s_ssd[tid][1] + s_ssd[tid][2] + s_ssd[tid][3];
        float mean = tot * (1.0f / 128.0f);
        out[OFF_COM + gt] = mean;
        out[OFF_COD + gt] = mean;
    }
}

// ---------------------------------------------------------------------------
extern "C" void kernel_launch(void* const* d_in, const int* in_sizes, int n_in,
                              void* d_out, int out_size, void* d_ws, size_t ws_size,
                              hipStream_t stream) {
    const float* x   = (const float*)d_in[0];
    const float* emb = (const float*)d_in[1];
    const float* z   = (const float*)d_in[2];
    float* out = (float*)d_out;

    unsigned short* Bp  = (unsigned short*)((char*)d_ws + WS_BP);
    float4* st4  = (float4*)((char*)d_ws + WS_ST);
    float*  Cgl  = (float*)((char*)d_ws + WS_C);
    float4* cd   = (float4*)((char*)d_ws + WS_CAND);
    double* Le   = (double*)((char*)d_ws + WS_LE);
    double* B2   = (double*)((char*)d_ws + WS_B2);
    double* Den  = (double*)((char*)d_ws + WS_DEN);

    hipLaunchKernelGGL(prep_c, dim3(TG_COUNT), dim3(256), 0, stream, x, Cgl);
    hipLaunchKernelGGL(prep_b, dim3(KK / 256), dim3(256), 0, stream,
                       emb, Bp, st4, Le, B2, Den);
    hipLaunchKernelGGL(vq_mfma, dim3(TG_COUNT * NSLICE), dim3(128), 0, stream,
                       x, Bp, st4, Cgl, cd);
    hipLaunchKernelGGL(finalize, dim3(TG_COUNT), dim3(256), 0, stream,
                       x, emb, z, cd, Cgl, Le, B2, Den, out);
}